// Round 4
// baseline (13045.233 us; speedup 1.0000x reference)
//
#include <hip/hip_runtime.h>

typedef __bf16 bf16;
typedef __bf16 bf16x8 __attribute__((ext_vector_type(8)));
typedef float f32x4 __attribute__((ext_vector_type(4)));

#define BKSZ 32
#define BKP  40   // padded LDS leading dim

__device__ __forceinline__ float b2f(bf16 v) { return (float)v; }
__device__ __forceinline__ bf16  f2b(float v) { return (bf16)v; }
__device__ __forceinline__ float gelu_f(float x) {
  return 0.5f * x * (1.0f + erff(x * 0.70710678118654752f));
}
__device__ __forceinline__ void split2(float v, bf16& h, bf16& l) {
  h = f2b(v); l = f2b(v - b2f(h));
}

// Detect input dtype: ln1_g[0]==1.0. f32 word = 0x3F800000. flag: 1=f32.
__global__ void detect_k(const void* g1, int* flag) {
  if (threadIdx.x == 0 && blockIdx.x == 0) {
    unsigned u = *(const unsigned*)g1;
    *flag = (u == 0x3F800000u) ? 1 : 0;
  }
}

// ---------------------------------------------------------------------------
// Precise GEMM via split-bf16: each f32 operand -> hi+lo bf16; 3 MFMAs per
// tile pair give ~f32 accuracy. A: f32 [M][K] (lda). B: if BT, f32 [N][K];
// else [K][N], dtype per dflag (nullptr or *dflag!=0 -> f32, else bf16 with
// lo=0). Per-z offsets: A += z*sAi, B += Bofs + z*sBi, C += z*sCi.
// EPI: 0 store, 2 gelu->store, 3 +=.  out = alpha*acc + bias.
// Block 256 = 4 waves, wave tile WM x WN of 16x16x32 MFMAs.
// ---------------------------------------------------------------------------
template<int BM, int BN, int WM, int WN, bool BT, int EPI>
__global__ __launch_bounds__(256) void pgemm_k(
    const float* __restrict__ A, const void* __restrict__ Bv,
    float* __restrict__ C,
    const void* __restrict__ biasv, const int* __restrict__ dflag,
    int K, int lda, int ldb, int ldc,
    long Bofs, long biasOfs, long sAi, long sBi, long sCi, float alpha)
{
  __shared__ alignas(16) bf16 Ah[BM * BKP];
  __shared__ alignas(16) bf16 Al[BM * BKP];
  __shared__ alignas(16) bf16 Bh[BN * BKP];
  __shared__ alignas(16) bf16 Bl[BN * BKP];

  const int tid  = threadIdx.x;
  const int lane = tid & 63;
  const int wid  = tid >> 6;
  const int z    = blockIdx.z;
  const bool f32b = (dflag == nullptr) || (*dflag != 0);

  const float* Ab = A + (long)z * sAi + (long)blockIdx.y * BM * lda;

  constexpr int WCOLS = BN / WN;
  const int wm = (wid / WCOLS) * WM;
  const int wn = (wid % WCOLS) * WN;
  constexpr int TM = WM / 16;
  constexpr int TN = WN / 16;

  f32x4 acc[TM][TN];
  const f32x4 zero = {0.f, 0.f, 0.f, 0.f};
#pragma unroll
  for (int i = 0; i < TM; i++)
#pragma unroll
    for (int j = 0; j < TN; j++) acc[i][j] = zero;

  const int lm = lane & 15;
  const int q  = lane >> 4;

  for (int kt = 0; kt < K; kt += BKSZ) {
    // ---- stage A tile (f32 -> hi/lo), 4 floats per thread-iter
    for (int idx = tid; idx < BM * (BKSZ / 4); idx += 256) {
      int m  = idx >> 3;
      int k0 = (idx & 7) * 4;
      float4 v = *reinterpret_cast<const float4*>(Ab + (long)m * lda + kt + k0);
      alignas(8) bf16 h[4], lo[4];
      split2(v.x, h[0], lo[0]); split2(v.y, h[1], lo[1]);
      split2(v.z, h[2], lo[2]); split2(v.w, h[3], lo[3]);
      *reinterpret_cast<uint2*>(&Ah[m * BKP + k0]) = *reinterpret_cast<uint2*>(h);
      *reinterpret_cast<uint2*>(&Al[m * BKP + k0]) = *reinterpret_cast<uint2*>(lo);
    }
    // ---- stage B tile into [n][k] hi/lo
    if (BT) {
      const float* Bb = (const float*)Bv + Bofs + (long)z * sBi + (long)blockIdx.x * BN * ldb;
      for (int idx = tid; idx < BN * (BKSZ / 4); idx += 256) {
        int n  = idx >> 3;
        int k0 = (idx & 7) * 4;
        float4 v = *reinterpret_cast<const float4*>(Bb + (long)n * ldb + kt + k0);
        alignas(8) bf16 h[4], lo[4];
        split2(v.x, h[0], lo[0]); split2(v.y, h[1], lo[1]);
        split2(v.z, h[2], lo[2]); split2(v.w, h[3], lo[3]);
        *reinterpret_cast<uint2*>(&Bh[n * BKP + k0]) = *reinterpret_cast<uint2*>(h);
        *reinterpret_cast<uint2*>(&Bl[n * BKP + k0]) = *reinterpret_cast<uint2*>(lo);
      }
    } else if (f32b) {
      const float* Bb = (const float*)Bv + Bofs + (long)z * sBi + blockIdx.x * BN;
      for (int idx = tid; idx < BKSZ * (BN / 4); idx += 256) {
        int k  = idx / (BN / 4);
        int n0 = (idx % (BN / 4)) * 4;
        float4 v = *reinterpret_cast<const float4*>(Bb + (long)(kt + k) * ldb + n0);
        bf16 h[4], lo[4];
        split2(v.x, h[0], lo[0]); split2(v.y, h[1], lo[1]);
        split2(v.z, h[2], lo[2]); split2(v.w, h[3], lo[3]);
#pragma unroll
        for (int j = 0; j < 4; j++) {
          Bh[(n0 + j) * BKP + k] = h[j];
          Bl[(n0 + j) * BKP + k] = lo[j];
        }
      }
    } else {
      const bf16* Bb = (const bf16*)Bv + Bofs + (long)z * sBi + blockIdx.x * BN;
      for (int idx = tid; idx < BKSZ * (BN / 4); idx += 256) {
        int k  = idx / (BN / 4);
        int n0 = (idx % (BN / 4)) * 4;
        alignas(8) bf16 v[4];
        *reinterpret_cast<uint2*>(v) =
            *reinterpret_cast<const uint2*>(Bb + (long)(kt + k) * ldb + n0);
#pragma unroll
        for (int j = 0; j < 4; j++) {
          Bh[(n0 + j) * BKP + k] = v[j];
          Bl[(n0 + j) * BKP + k] = f2b(0.0f);
        }
      }
    }
    __syncthreads();

    bf16x8 ah[TM], al[TM], bh[TN], bl[TN];
#pragma unroll
    for (int i = 0; i < TM; i++) {
      int r = (wm + i * 16 + lm) * BKP + q * 8;
      ah[i] = *reinterpret_cast<const bf16x8*>(&Ah[r]);
      al[i] = *reinterpret_cast<const bf16x8*>(&Al[r]);
    }
#pragma unroll
    for (int j = 0; j < TN; j++) {
      int r = (wn + j * 16 + lm) * BKP + q * 8;
      bh[j] = *reinterpret_cast<const bf16x8*>(&Bh[r]);
      bl[j] = *reinterpret_cast<const bf16x8*>(&Bl[r]);
    }
#pragma unroll
    for (int i = 0; i < TM; i++)
#pragma unroll
      for (int j = 0; j < TN; j++) {
        f32x4 a = acc[i][j];
        a = __builtin_amdgcn_mfma_f32_16x16x32_bf16(al[i], bh[j], a, 0, 0, 0);
        a = __builtin_amdgcn_mfma_f32_16x16x32_bf16(ah[i], bl[j], a, 0, 0, 0);
        a = __builtin_amdgcn_mfma_f32_16x16x32_bf16(ah[i], bh[j], a, 0, 0, 0);
        acc[i][j] = a;
      }
    __syncthreads();
  }

  // ---- epilogue: C/D layout col=lane&15, row=(lane>>4)*4+reg
  const long row0 = (long)blockIdx.y * BM + wm;
  const int  col0 = blockIdx.x * BN + wn;
  float* Cb = C + (long)z * sCi;
#pragma unroll
  for (int i = 0; i < TM; i++) {
#pragma unroll
    for (int j = 0; j < TN; j++) {
      int gn = col0 + j * 16 + lm;
      float bv = 0.0f;
      if (biasv)
        bv = f32b ? ((const float*)biasv)[biasOfs + gn]
                  : b2f(((const bf16*)biasv)[biasOfs + gn]);
#pragma unroll
      for (int r = 0; r < 4; r++) {
        long gm   = row0 + i * 16 + q * 4 + r;
        long cidx = gm * (long)ldc + gn;
        float v = alpha * acc[i][j][r] + bv;
        if (EPI == 0)      Cb[cidx] = v;
        else if (EPI == 2) Cb[cidx] = gelu_f(v);
        else               Cb[cidx] += v;
      }
    }
  }
}

// ---------------------------------------------------------------------------
// LayerNorm: one wave per token (1024 f32), f32 out. g/b dtype by flag.
// ---------------------------------------------------------------------------
__global__ __launch_bounds__(256) void ln_k(const float* __restrict__ x,
                                            const void* __restrict__ g,
                                            const void* __restrict__ b,
                                            int ofs, const int* __restrict__ dflag,
                                            float* __restrict__ out)
{
  const bool f32in = (*dflag != 0);
  const int lane = threadIdx.x & 63;
  const int t    = blockIdx.x * 4 + (threadIdx.x >> 6);
  const float* row = x + (long)t * 1024;
  float4 v[4];
  float s = 0.f, sq = 0.f;
#pragma unroll
  for (int c = 0; c < 4; c++) {
    v[c] = reinterpret_cast<const float4*>(row)[lane + c * 64];
    s  += v[c].x + v[c].y + v[c].z + v[c].w;
    sq += v[c].x * v[c].x + v[c].y * v[c].y + v[c].z * v[c].z + v[c].w * v[c].w;
  }
#pragma unroll
  for (int o = 32; o > 0; o >>= 1) { s += __shfl_xor(s, o); sq += __shfl_xor(sq, o); }
  float m    = s * (1.0f / 1024.0f);
  float var  = sq * (1.0f / 1024.0f) - m * m;
  float rstd = 1.0f / sqrtf(var + 1e-5f);
  float* orow = out + (long)t * 1024;
#pragma unroll
  for (int c = 0; c < 4; c++) {
    int col = (lane + c * 64) * 4;
    const float* fv = reinterpret_cast<const float*>(&v[c]);
    float4 o;
    float* ov = reinterpret_cast<float*>(&o);
#pragma unroll
    for (int e = 0; e < 4; e++) {
      float gv = f32in ? ((const float*)g)[ofs + col + e] : b2f(((const bf16*)g)[ofs + col + e]);
      float bb = f32in ? ((const float*)b)[ofs + col + e] : b2f(((const bf16*)b)[ofs + col + e]);
      ov[e] = (fv[e] - m) * rstd * gv + bb;
    }
    *reinterpret_cast<float4*>(orow + col) = o;
  }
}

// ---------------------------------------------------------------------------
// Router: one wave per token; top-2 (ties kept) softmax -> f32 weights.
// ---------------------------------------------------------------------------
__global__ __launch_bounds__(256) void router_k(const float* __restrict__ x,
    const void* __restrict__ Wr, const void* __restrict__ br,
    int ofsW, int ofsB, const int* __restrict__ dflag,
    float* __restrict__ wts)
{
  const bool f32in = (*dflag != 0);
  const int lane = threadIdx.x & 63;
  const int t    = blockIdx.x * 4 + (threadIdx.x >> 6);
  float acc[8];
#pragma unroll
  for (int e = 0; e < 8; e++) acc[e] = 0.f;
  const float* row = x + (long)t * 1024;
  for (int c = 0; c < 16; c++) {
    int d = c * 64 + lane;
    float xv = row[d];
    if (f32in) {
      const float4* p = reinterpret_cast<const float4*>((const float*)Wr + ofsW + d * 8);
      float4 w0 = p[0], w1 = p[1];
      acc[0] += xv * w0.x; acc[1] += xv * w0.y; acc[2] += xv * w0.z; acc[3] += xv * w0.w;
      acc[4] += xv * w1.x; acc[5] += xv * w1.y; acc[6] += xv * w1.z; acc[7] += xv * w1.w;
    } else {
      bf16x8 w = *reinterpret_cast<const bf16x8*>((const bf16*)Wr + ofsW + d * 8);
#pragma unroll
      for (int e = 0; e < 8; e++) acc[e] += xv * (float)w[e];
    }
  }
#pragma unroll
  for (int o = 32; o > 0; o >>= 1)
#pragma unroll
    for (int e = 0; e < 8; e++) acc[e] += __shfl_xor(acc[e], o);
#pragma unroll
  for (int e = 0; e < 8; e++)
    acc[e] += f32in ? ((const float*)br)[ofsB + e] : b2f(((const bf16*)br)[ofsB + e]);
  float m1 = -1e30f, m2 = -1e30f;
#pragma unroll
  for (int e = 0; e < 8; e++) {
    float v = acc[e];
    if (v > m1) { m2 = m1; m1 = v; }
    else if (v > m2) m2 = v;
  }
  float Z = 0.f, p[8];
#pragma unroll
  for (int e = 0; e < 8; e++) {
    p[e] = (acc[e] >= m2) ? __expf(acc[e] - m1) : 0.f;
    Z += p[e];
  }
  float inv = 1.0f / Z;
  if (lane < 8) wts[t * 8 + lane] = p[lane] * inv;
}

// ---------------------------------------------------------------------------
// In-place row softmax on f32 scores: one wave per 1024-wide row.
// ---------------------------------------------------------------------------
__global__ __launch_bounds__(256) void softmax_k(float* __restrict__ S)
{
  const int lane = threadIdx.x & 63;
  const long r   = (long)blockIdx.x * 4 + (threadIdx.x >> 6);
  float* row = S + r * 1024;
  float4 v[4];
#pragma unroll
  for (int c = 0; c < 4; c++) v[c] = reinterpret_cast<const float4*>(row + lane * 16)[c];
  float* f = reinterpret_cast<float*>(v);
  float mx = -1e30f;
#pragma unroll
  for (int k = 0; k < 16; k++) mx = fmaxf(mx, f[k]);
#pragma unroll
  for (int o = 32; o > 0; o >>= 1) mx = fmaxf(mx, __shfl_xor(mx, o));
  float s = 0.f;
#pragma unroll
  for (int k = 0; k < 16; k++) { f[k] = __expf(f[k] - mx); s += f[k]; }
#pragma unroll
  for (int o = 32; o > 0; o >>= 1) s += __shfl_xor(s, o);
  float inv = 1.0f / s;
#pragma unroll
  for (int k = 0; k < 16; k++) f[k] *= inv;
#pragma unroll
  for (int c = 0; c < 4; c++) reinterpret_cast<float4*>(row + lane * 16)[c] = v[c];
}

// ---------------------------------------------------------------------------
// Elementwise kernels
// ---------------------------------------------------------------------------
__global__ __launch_bounds__(256) void inx_k(const void* __restrict__ xin,
                                             const int* __restrict__ dflag,
                                             float* __restrict__ out) {
  long i = (long)blockIdx.x * 256 + threadIdx.x;
  out[i] = (*dflag != 0) ? ((const float*)xin)[i] : b2f(((const bf16*)xin)[i]);
}
// ytf = gelu(t0)*t1 ; y = w[token][0] * gelu(ytf)
__global__ __launch_bounds__(256) void ytf_k(const float* __restrict__ t0,
                                             const float* __restrict__ t1,
                                             const float* __restrict__ wl,
                                             float* __restrict__ ytf,
                                             float* __restrict__ y) {
  long i = (long)blockIdx.x * 256 + threadIdx.x;
  float v = gelu_f(t0[i]) * t1[i];
  ytf[i] = v;
  y[i] = wl[(i >> 10) * 8] * gelu_f(v);
}
// y += w_e * (P*ytf + A)
__global__ __launch_bounds__(256) void eacc_k(const float* __restrict__ Px,
                                              const float* __restrict__ Ax,
                                              const float* __restrict__ ytf,
                                              const float* __restrict__ wl,
                                              int e, float* __restrict__ y) {
  long i = (long)blockIdx.x * 256 + threadIdx.x;
  float w = wl[(i >> 10) * 8 + e];
  if (w != 0.f) y[i] += w * (Px[i] * ytf[i] + Ax[i]);
}
// Final output: x (4194304) then router weights (65536), dtype by flag.
__global__ __launch_bounds__(256) void outw_k(const float* __restrict__ xr,
                                              const float* __restrict__ wts,
                                              const int* __restrict__ dflag,
                                              void* __restrict__ out) {
  long i = (long)blockIdx.x * 256 + threadIdx.x;
  float v = (i < 4194304) ? xr[i] : wts[i - 4194304];
  if (*dflag != 0) ((float*)out)[i] = v;
  else             ((bf16*)out)[i]  = f2b(v);
}

// ---------------------------------------------------------------------------
extern "C" void kernel_launch(void* const* d_in, const int* in_sizes, int n_in,
                              void* d_out, int out_size, void* d_ws, size_t ws_size,
                              hipStream_t stream)
{
  (void)in_sizes; (void)n_in; (void)out_size; (void)ws_size;

  // ---- workspace plan (~160.3 MB, all f32 activations) ----
  char* w = (char*)d_ws;
  float* x_res = (float*)w; w += 16777216;   // [4096][1024] residual stream
  float* yac   = (float*)w; w += 16777216;   // [4096][1024] MoE accumulator
  float* wts   = (float*)w; w += 262144;     // [2][4096][8] router weights
  int*  flag   = (int*)w;   w += 256;        // dtype flag (1 = f32 inputs)
  float* hbuf  = (float*)w; w += 16777216;   // [4096][1024] LN out
  float* qkvf  = (float*)w; w += 50331648;   // [4096][3072]
  float* obuf  = (float*)w; w += 16777216;   // [4096][1024] attn out
  float* ytff  = (float*)w; w += 16777216;   // [4096][1024] FiLM trunk
  // R1 (32 MB), time-aliased: score chunk | tA+tB | adaptor hidden chunk
  char* R1 = w;             w += 33554432;
  float* Sf  = (float*)R1;                   // [16][512][1024] scores (per b, half)
  float* tA  = (float*)R1;                   // [4096][1024]
  float* tB  = (float*)(R1 + 16777216);      // [4096][1024]
  float* a1c = (float*)R1;                   // [1024][4096] adaptor hidden chunk

  dim3 blk(256);
  detect_k<<<1, 64, 0, stream>>>(d_in[1], flag);
  inx_k<<<16384, blk, 0, stream>>>(d_in[0], flag, x_res);

  for (int l = 0; l < 2; l++) {
    // ---- PreNorm attention ----
    ln_k<<<1024, blk, 0, stream>>>(x_res, d_in[1], d_in[2], l * 1024, flag, hbuf);
    pgemm_k<128,128,64,64,false,0><<<dim3(24, 32, 1), blk, 0, stream>>>(
        hbuf, d_in[3], qkvf, d_in[4], flag,
        1024, 1024, 3072, 3072, (long)l * 3145728, (long)l * 3072, 0, 0, 0, 1.0f);
    for (int b = 0; b < 4; b++) {
      for (int hq = 0; hq < 2; hq++) {
        const float* Qb = qkvf + ((long)b * 1024 + hq * 512) * 3072;
        // scores[head][512 q][1024 keys] = Q K^T / 8
        pgemm_k<128,128,64,64,true,0><<<dim3(8, 4, 16), blk, 0, stream>>>(
            Qb, qkvf, Sf, nullptr, nullptr,
            64, 3072, 3072, 1024, (long)b * 3145728 + 1024, 0, 64, 64, 524288, 0.125f);
        softmax_k<<<2048, blk, 0, stream>>>(Sf);
        // o = P V
        pgemm_k<128,64,64,32,false,0><<<dim3(1, 4, 16), blk, 0, stream>>>(
            Sf, qkvf, obuf + ((long)b * 1024 + hq * 512) * 1024, nullptr, nullptr,
            1024, 1024, 3072, 1024, (long)b * 3145728 + 2048, 0, 524288, 64, 64, 1.0f);
      }
    }
    pgemm_k<128,128,64,64,false,3><<<dim3(8, 32, 1), blk, 0, stream>>>(
        obuf, d_in[5], x_res, d_in[6], flag,
        1024, 1024, 1024, 1024, (long)l * 1048576, (long)l * 1024, 0, 0, 0, 1.0f);

    // ---- Router (post-attention x) ----
    float* wl = wts + (long)l * 32768;
    router_k<<<1024, blk, 0, stream>>>(x_res, d_in[7], d_in[8],
                                       l * 8192, l * 8, flag, wl);

    // ---- FiLM trunk ----
    ln_k<<<1024, blk, 0, stream>>>(x_res, d_in[13], d_in[14], l * 1024, flag, hbuf);
    pgemm_k<128,128,64,64,false,0><<<dim3(8, 32, 1), blk, 0, stream>>>(
        hbuf, d_in[15], tA, d_in[16], flag,
        1024, 1024, 1024, 1024, (long)l * 1048576, (long)l * 1024, 0, 0, 0, 1.0f);
    pgemm_k<128,128,64,64,false,0><<<dim3(8, 32, 1), blk, 0, stream>>>(
        hbuf, d_in[17], tB, d_in[18], flag,
        1024, 1024, 1024, 1024, (long)l * 1048576, (long)l * 1024, 0, 0, 0, 1.0f);
    ytf_k<<<16384, blk, 0, stream>>>(tA, tB, wl, ytff, yac);

    // ---- Experts 1..7 (dense) ----
    for (int e = 0; e < 7; e++) {
      long wofs = ((long)l * 7 + e) * 1048576;
      long bofs = ((long)l * 7 + e) * 1024;
      pgemm_k<128,128,64,64,false,0><<<dim3(8, 32, 1), blk, 0, stream>>>(
          ytff, d_in[19], tA, d_in[20], flag,
          1024, 1024, 1024, 1024, wofs, bofs, 0, 0, 0, 1.0f);
      pgemm_k<128,128,64,64,false,0><<<dim3(8, 32, 1), blk, 0, stream>>>(
          ytff, d_in[21], tB, d_in[22], flag,
          1024, 1024, 1024, 1024, wofs, bofs, 0, 0, 0, 1.0f);
      eacc_k<<<16384, blk, 0, stream>>>(tA, tB, ytff, wl, e + 1, yac);
    }

    // ---- Adaptor MLP + residual (4 token chunks of 1024) ----
    for (int c = 0; c < 4; c++) {
      pgemm_k<128,128,64,64,false,2><<<dim3(32, 8, 1), blk, 0, stream>>>(
          yac + (long)c * 1048576, d_in[9], a1c, d_in[10], flag,
          1024, 1024, 4096, 4096, (long)l * 4194304, (long)l * 4096, 0, 0, 0, 1.0f);
      pgemm_k<128,128,64,64,false,3><<<dim3(8, 8, 1), blk, 0, stream>>>(
          a1c, d_in[11], x_res + (long)c * 1048576, d_in[12], flag,
          4096, 4096, 1024, 1024, (long)l * 4194304, (long)l * 1024, 0, 0, 0, 1.0f);
    }
  }

  outw_k<<<16640, blk, 0, stream>>>(x_res, wts, flag, d_out);
}

// Round 5
// 5321.564 us; speedup vs baseline: 2.4514x; 2.4514x over previous
//
#include <hip/hip_runtime.h>

typedef __bf16 bf16;
typedef __bf16 bf16x8 __attribute__((ext_vector_type(8)));
typedef float f32x4 __attribute__((ext_vector_type(4)));

#define BKSZ 32
#define BKP  40

__device__ __forceinline__ float b2f(bf16 v) { return (float)v; }
__device__ __forceinline__ bf16  f2b(float v) { return (bf16)v; }
__device__ __forceinline__ float gelu_f(float x) {
  return 0.5f * x * (1.0f + erff(x * 0.70710678118654752f));
}
__device__ __forceinline__ void split2(float v, bf16& h, bf16& l) {
  h = f2b(v); l = f2b(v - b2f(h));
}

// Detect input dtype: ln1_g[0]==1.0. f32 word = 0x3F800000. ctrl[0]: 1=f32.
__global__ void detect_k(const void* g1, int* ctrl) {
  if (threadIdx.x == 0 && blockIdx.x == 0) {
    unsigned u = *(const unsigned*)g1;
    ctrl[0] = (u == 0x3F800000u) ? 1 : 0;
  }
}

// ---------------------------------------------------------------------------
// Precise GEMM via split-bf16 (hi/lo, 3 MFMAs). A: f32 [M][K] (lda).
// B: if BT, f32 [N][K]; else [K][N], dtype per dflag (nullptr/!=0 -> f32).
// Two-level z: zo=z/bdiv, zi=z%bdiv; operand += zo*s?o + zi*s?i.
// Gather mode (elist != nullptr): A rows indirected via elist[z*4096+row]
// (valid for row < ecnt[z], else token 0); C rows compact at eoff[z]+row;
// blocks with row0 >= padded count exit early.
// EPI: 0 store, 2 gelu->store, 3 +=, 4 atomicAdd, 7 C = C*Yt[token]+v.
// out v = alpha*acc + bias[biasOfs + zi*biasZ + col].
// ---------------------------------------------------------------------------
template<int BM, int BN, int WM, int WN, bool BT, int EPI>
__global__ __launch_bounds__(256) void pgemm_k(
    const float* __restrict__ A, const void* __restrict__ Bv,
    float* __restrict__ C,
    const void* __restrict__ biasv, const int* __restrict__ dflag,
    const int* __restrict__ elist, const int* __restrict__ ecnt,
    const int* __restrict__ eoff, const float* __restrict__ Yt,
    int K, int lda, int ldb, int ldc,
    long Bofs, long biasOfs, long biasZ,
    long sAo, long sAi, long sBo, long sBi, long sCo, long sCi,
    int bdiv, float alpha)
{
  __shared__ alignas(16) bf16 Ah[BM * BKP];
  __shared__ alignas(16) bf16 Al[BM * BKP];
  __shared__ alignas(16) bf16 Bh[BN * BKP];
  __shared__ alignas(16) bf16 Bl[BN * BKP];
  __shared__ int ridx[BM];

  const int tid  = threadIdx.x;
  const int lane = tid & 63;
  const int wid  = tid >> 6;
  const int z    = blockIdx.z;
  const int zo   = z / bdiv;
  const int zi   = z % bdiv;
  const bool f32b = (dflag == nullptr) || (*dflag != 0);

  const float* Ab;
  long Crow0;
  if (elist) {
    int cntz = ecnt[z];
    int padc = (cntz + BM - 1) & ~(BM - 1);
    if ((int)blockIdx.y * BM >= padc) return;
    if (tid < BM) {
      int grow = blockIdx.y * BM + tid;
      ridx[tid] = (grow < cntz) ? elist[z * 4096 + grow] : 0;
    }
    __syncthreads();
    Ab = A;  // per-row base from ridx
    Crow0 = (long)eoff[z] + (long)blockIdx.y * BM;
  } else {
    Ab = A + (long)zo * sAo + (long)zi * sAi + (long)blockIdx.y * BM * lda;
    Crow0 = (long)blockIdx.y * BM;
  }

  constexpr int WCOLS = BN / WN;
  const int wm = (wid / WCOLS) * WM;
  const int wn = (wid % WCOLS) * WN;
  constexpr int TM = WM / 16;
  constexpr int TN = WN / 16;

  f32x4 acc[TM][TN];
  const f32x4 zero = {0.f, 0.f, 0.f, 0.f};
#pragma unroll
  for (int i = 0; i < TM; i++)
#pragma unroll
    for (int j = 0; j < TN; j++) acc[i][j] = zero;

  const int lm = lane & 15;
  const int q  = lane >> 4;

  for (int kt = 0; kt < K; kt += BKSZ) {
    // ---- stage A tile (f32 -> hi/lo)
    for (int idx = tid; idx < BM * (BKSZ / 4); idx += 256) {
      int m  = idx >> 3;
      int k0 = (idx & 7) * 4;
      const float* src = elist ? (A + (long)ridx[m] * lda + kt + k0)
                               : (Ab + (long)m * lda + kt + k0);
      float4 v = *reinterpret_cast<const float4*>(src);
      alignas(8) bf16 h[4], lo[4];
      split2(v.x, h[0], lo[0]); split2(v.y, h[1], lo[1]);
      split2(v.z, h[2], lo[2]); split2(v.w, h[3], lo[3]);
      *reinterpret_cast<uint2*>(&Ah[m * BKP + k0]) = *reinterpret_cast<uint2*>(h);
      *reinterpret_cast<uint2*>(&Al[m * BKP + k0]) = *reinterpret_cast<uint2*>(lo);
    }
    // ---- stage B tile into [n][k] hi/lo
    if (BT) {
      const float* Bb = (const float*)Bv + Bofs + (long)zo * sBo + (long)zi * sBi
                        + (long)blockIdx.x * BN * ldb;
      for (int idx = tid; idx < BN * (BKSZ / 4); idx += 256) {
        int n  = idx >> 3;
        int k0 = (idx & 7) * 4;
        float4 v = *reinterpret_cast<const float4*>(Bb + (long)n * ldb + kt + k0);
        alignas(8) bf16 h[4], lo[4];
        split2(v.x, h[0], lo[0]); split2(v.y, h[1], lo[1]);
        split2(v.z, h[2], lo[2]); split2(v.w, h[3], lo[3]);
        *reinterpret_cast<uint2*>(&Bh[n * BKP + k0]) = *reinterpret_cast<uint2*>(h);
        *reinterpret_cast<uint2*>(&Bl[n * BKP + k0]) = *reinterpret_cast<uint2*>(lo);
      }
    } else if (f32b) {
      const float* Bb = (const float*)Bv + Bofs + (long)zo * sBo + (long)zi * sBi
                        + blockIdx.x * BN;
      for (int idx = tid; idx < BKSZ * (BN / 4); idx += 256) {
        int k  = idx / (BN / 4);
        int n0 = (idx % (BN / 4)) * 4;
        float4 v = *reinterpret_cast<const float4*>(Bb + (long)(kt + k) * ldb + n0);
        bf16 h[4], lo[4];
        split2(v.x, h[0], lo[0]); split2(v.y, h[1], lo[1]);
        split2(v.z, h[2], lo[2]); split2(v.w, h[3], lo[3]);
#pragma unroll
        for (int j = 0; j < 4; j++) {
          Bh[(n0 + j) * BKP + k] = h[j];
          Bl[(n0 + j) * BKP + k] = lo[j];
        }
      }
    } else {
      const bf16* Bb = (const bf16*)Bv + Bofs + (long)zo * sBo + (long)zi * sBi
                       + blockIdx.x * BN;
      for (int idx = tid; idx < BKSZ * (BN / 4); idx += 256) {
        int k  = idx / (BN / 4);
        int n0 = (idx % (BN / 4)) * 4;
        alignas(8) bf16 v[4];
        *reinterpret_cast<uint2*>(v) =
            *reinterpret_cast<const uint2*>(Bb + (long)(kt + k) * ldb + n0);
#pragma unroll
        for (int j = 0; j < 4; j++) {
          Bh[(n0 + j) * BKP + k] = v[j];
          Bl[(n0 + j) * BKP + k] = f2b(0.0f);
        }
      }
    }
    __syncthreads();

    bf16x8 ah[TM], al[TM], bh[TN], bl[TN];
#pragma unroll
    for (int i = 0; i < TM; i++) {
      int r = (wm + i * 16 + lm) * BKP + q * 8;
      ah[i] = *reinterpret_cast<const bf16x8*>(&Ah[r]);
      al[i] = *reinterpret_cast<const bf16x8*>(&Al[r]);
    }
#pragma unroll
    for (int j = 0; j < TN; j++) {
      int r = (wn + j * 16 + lm) * BKP + q * 8;
      bh[j] = *reinterpret_cast<const bf16x8*>(&Bh[r]);
      bl[j] = *reinterpret_cast<const bf16x8*>(&Bl[r]);
    }
#pragma unroll
    for (int i = 0; i < TM; i++)
#pragma unroll
      for (int j = 0; j < TN; j++) {
        f32x4 a = acc[i][j];
        a = __builtin_amdgcn_mfma_f32_16x16x32_bf16(al[i], bh[j], a, 0, 0, 0);
        a = __builtin_amdgcn_mfma_f32_16x16x32_bf16(ah[i], bl[j], a, 0, 0, 0);
        a = __builtin_amdgcn_mfma_f32_16x16x32_bf16(ah[i], bh[j], a, 0, 0, 0);
        acc[i][j] = a;
      }
    __syncthreads();
  }

  // ---- epilogue: C/D layout col=lane&15, row=(lane>>4)*4+reg
  const int col0 = blockIdx.x * BN + wn;
  float* Cb = C + (elist ? 0L : ((long)zo * sCo + (long)zi * sCi));
#pragma unroll
  for (int i = 0; i < TM; i++) {
#pragma unroll
    for (int j = 0; j < TN; j++) {
      int gn = col0 + j * 16 + lm;
      float bv = 0.0f;
      if (biasv) {
        long bo = biasOfs + (long)zi * biasZ + gn;
        bv = f32b ? ((const float*)biasv)[bo] : b2f(((const bf16*)biasv)[bo]);
      }
#pragma unroll
      for (int r = 0; r < 4; r++) {
        int  lrow = wm + i * 16 + q * 4 + r;
        long cidx = (Crow0 + lrow) * (long)ldc + gn;
        float v = alpha * acc[i][j][r] + bv;
        if (EPI == 0)      Cb[cidx] = v;
        else if (EPI == 2) Cb[cidx] = gelu_f(v);
        else if (EPI == 3) Cb[cidx] += v;
        else if (EPI == 4) atomicAdd(&Cb[cidx], v);
        else if (EPI == 7) {
          int tok = ridx[lrow];
          float yt = Yt[(long)tok * 1024 + gn];
          Cb[cidx] = Cb[cidx] * yt + v;
        }
      }
    }
  }
}

// ---------------------------------------------------------------------------
// LayerNorm: one wave per token (1024 f32), f32 out.
// ---------------------------------------------------------------------------
__global__ __launch_bounds__(256) void ln_k(const float* __restrict__ x,
                                            const void* __restrict__ g,
                                            const void* __restrict__ b,
                                            int ofs, const int* __restrict__ dflag,
                                            float* __restrict__ out)
{
  const bool f32in = (*dflag != 0);
  const int lane = threadIdx.x & 63;
  const int t    = blockIdx.x * 4 + (threadIdx.x >> 6);
  const float* row = x + (long)t * 1024;
  float4 v[4];
  float s = 0.f, sq = 0.f;
#pragma unroll
  for (int c = 0; c < 4; c++) {
    v[c] = reinterpret_cast<const float4*>(row)[lane + c * 64];
    s  += v[c].x + v[c].y + v[c].z + v[c].w;
    sq += v[c].x * v[c].x + v[c].y * v[c].y + v[c].z * v[c].z + v[c].w * v[c].w;
  }
#pragma unroll
  for (int o = 32; o > 0; o >>= 1) { s += __shfl_xor(s, o); sq += __shfl_xor(sq, o); }
  float m    = s * (1.0f / 1024.0f);
  float var  = sq * (1.0f / 1024.0f) - m * m;
  float rstd = 1.0f / sqrtf(var + 1e-5f);
  float* orow = out + (long)t * 1024;
#pragma unroll
  for (int c = 0; c < 4; c++) {
    int col = (lane + c * 64) * 4;
    const float* fv = reinterpret_cast<const float*>(&v[c]);
    float4 o;
    float* ov = reinterpret_cast<float*>(&o);
#pragma unroll
    for (int e = 0; e < 4; e++) {
      float gv = f32in ? ((const float*)g)[ofs + col + e] : b2f(((const bf16*)g)[ofs + col + e]);
      float bb = f32in ? ((const float*)b)[ofs + col + e] : b2f(((const bf16*)b)[ofs + col + e]);
      ov[e] = (fv[e] - m) * rstd * gv + bb;
    }
    *reinterpret_cast<float4*>(orow + col) = o;
  }
}

// ---------------------------------------------------------------------------
// Router + top-2 + per-expert list building. cnt[7] must be zeroed first.
// ---------------------------------------------------------------------------
__global__ __launch_bounds__(256) void router_k(const float* __restrict__ x,
    const void* __restrict__ Wr, const void* __restrict__ br,
    int ofsW, int ofsB, const int* __restrict__ dflag,
    float* __restrict__ wts, int* __restrict__ cnt, int* __restrict__ list)
{
  const bool f32in = (*dflag != 0);
  const int lane = threadIdx.x & 63;
  const int t    = blockIdx.x * 4 + (threadIdx.x >> 6);
  float acc[8];
#pragma unroll
  for (int e = 0; e < 8; e++) acc[e] = 0.f;
  const float* row = x + (long)t * 1024;
  for (int c = 0; c < 16; c++) {
    int d = c * 64 + lane;
    float xv = row[d];
    if (f32in) {
      const float4* p = reinterpret_cast<const float4*>((const float*)Wr + ofsW + d * 8);
      float4 w0 = p[0], w1 = p[1];
      acc[0] += xv * w0.x; acc[1] += xv * w0.y; acc[2] += xv * w0.z; acc[3] += xv * w0.w;
      acc[4] += xv * w1.x; acc[5] += xv * w1.y; acc[6] += xv * w1.z; acc[7] += xv * w1.w;
    } else {
      bf16x8 w = *reinterpret_cast<const bf16x8*>((const bf16*)Wr + ofsW + d * 8);
#pragma unroll
      for (int e = 0; e < 8; e++) acc[e] += xv * (float)w[e];
    }
  }
#pragma unroll
  for (int o = 32; o > 0; o >>= 1)
#pragma unroll
    for (int e = 0; e < 8; e++) acc[e] += __shfl_xor(acc[e], o);
#pragma unroll
  for (int e = 0; e < 8; e++)
    acc[e] += f32in ? ((const float*)br)[ofsB + e] : b2f(((const bf16*)br)[ofsB + e]);
  float m1 = -1e30f, m2 = -1e30f;
#pragma unroll
  for (int e = 0; e < 8; e++) {
    float v = acc[e];
    if (v > m1) { m2 = m1; m1 = v; }
    else if (v > m2) m2 = v;
  }
  float Z = 0.f, p[8];
#pragma unroll
  for (int e = 0; e < 8; e++) {
    p[e] = (acc[e] >= m2) ? __expf(acc[e] - m1) : 0.f;
    Z += p[e];
  }
  float inv = 1.0f / Z;
  if (lane < 8) {
    wts[t * 8 + lane] = p[lane] * inv;
    if (lane >= 1 && p[lane] > 0.f) {
      int pos = atomicAdd(&cnt[lane - 1], 1);
      list[(lane - 1) * 4096 + pos] = t;
    }
  }
}

// off[e] = prefix sum of 128-padded counts
__global__ void off_k(const int* __restrict__ cnt, int* __restrict__ off) {
  if (threadIdx.x == 0 && blockIdx.x == 0) {
    int o = 0;
    for (int e = 0; e < 7; e++) { off[e] = o; o += (cnt[e] + 127) & ~127; }
  }
}
__global__ void zcnt_k(int* __restrict__ cnt) {
  if (threadIdx.x < 7 && blockIdx.x == 0) cnt[threadIdx.x] = 0;
}
__global__ __launch_bounds__(256) void zero_k(float* __restrict__ p) {
  p[(long)blockIdx.x * 256 + threadIdx.x] = 0.f;
}

// ---------------------------------------------------------------------------
// In-place row softmax on f32 scores: one wave per 1024-wide row.
// ---------------------------------------------------------------------------
__global__ __launch_bounds__(256) void softmax_k(float* __restrict__ S)
{
  const int lane = threadIdx.x & 63;
  const long r   = (long)blockIdx.x * 4 + (threadIdx.x >> 6);
  float* row = S + r * 1024;
  float4 v[4];
#pragma unroll
  for (int c = 0; c < 4; c++) v[c] = reinterpret_cast<const float4*>(row + lane * 16)[c];
  float* f = reinterpret_cast<float*>(v);
  float mx = -1e30f;
#pragma unroll
  for (int k = 0; k < 16; k++) mx = fmaxf(mx, f[k]);
#pragma unroll
  for (int o = 32; o > 0; o >>= 1) mx = fmaxf(mx, __shfl_xor(mx, o));
  float s = 0.f;
#pragma unroll
  for (int k = 0; k < 16; k++) { f[k] = __expf(f[k] - mx); s += f[k]; }
#pragma unroll
  for (int o = 32; o > 0; o >>= 1) s += __shfl_xor(s, o);
  float inv = 1.0f / s;
#pragma unroll
  for (int k = 0; k < 16; k++) f[k] *= inv;
#pragma unroll
  for (int c = 0; c < 4; c++) reinterpret_cast<float4*>(row + lane * 16)[c] = v[c];
}

// ---------------------------------------------------------------------------
// Elementwise
// ---------------------------------------------------------------------------
__global__ __launch_bounds__(256) void inx_k(const void* __restrict__ xin,
                                             const int* __restrict__ dflag,
                                             float* __restrict__ out) {
  long i = (long)blockIdx.x * 256 + threadIdx.x;
  out[i] = (*dflag != 0) ? ((const float*)xin)[i] : b2f(((const bf16*)xin)[i]);
}
// ytf = gelu(t0)*t1 ; yac = w0 * gelu(ytf)
__global__ __launch_bounds__(256) void ytf_k(const float* __restrict__ t0,
                                             const float* __restrict__ t1,
                                             const float* __restrict__ wl,
                                             float* __restrict__ ytf,
                                             float* __restrict__ y) {
  long i = (long)blockIdx.x * 256 + threadIdx.x;
  float v = gelu_f(t0[i]) * t1[i];
  ytf[i] = v;
  y[i] = wl[(i >> 10) * 8] * gelu_f(v);
}
// scatter: yac[token] += w_e * eo[pair]
__global__ __launch_bounds__(256) void scatter_k(const int* __restrict__ list,
    const int* __restrict__ cnt, const int* __restrict__ off,
    const float* __restrict__ wl, const float* __restrict__ eo,
    float* __restrict__ yac)
{
  int e  = blockIdx.x >> 5;
  int s0 = (blockIdx.x & 31) * 128;
  int ce = cnt[e];
  if (s0 >= ce) return;
  int send = min(s0 + 128, ce);
  long base = (long)off[e] * 1024;
  for (int s = s0; s < send; s++) {
    int t = list[e * 4096 + s];
    float wv = wl[t * 8 + e + 1];
    const float* src = eo + base + (long)s * 1024;
    float* dst = yac + (long)t * 1024;
    for (int c = threadIdx.x; c < 1024; c += 256)
      atomicAdd(&dst[c], wv * src[c]);
  }
}
// Final output: x (4194304) then router weights (65536), dtype by flag.
__global__ __launch_bounds__(256) void outw_k(const float* __restrict__ xr,
                                              const float* __restrict__ wts,
                                              const int* __restrict__ dflag,
                                              void* __restrict__ out) {
  long i = (long)blockIdx.x * 256 + threadIdx.x;
  float v = (i < 4194304) ? xr[i] : wts[i - 4194304];
  if (*dflag != 0) ((float*)out)[i] = v;
  else             ((bf16*)out)[i]  = f2b(v);
}

// ---------------------------------------------------------------------------
extern "C" void kernel_launch(void* const* d_in, const int* in_sizes, int n_in,
                              void* d_out, int out_size, void* d_ws, size_t ws_size,
                              hipStream_t stream)
{
  (void)in_sizes; (void)n_in; (void)out_size; (void)ws_size;

  // ---- workspace plan (~160.4 MB, time-aliased) ----
  char* w = (char*)d_ws;
  float* x_res = (float*)w; w += 16777216;   // [4096][1024] residual
  float* yac   = (float*)w; w += 16777216;   // MoE accumulator | attn obuf
  float* obuf  = yac;
  float* wts   = (float*)w; w += 262144;     // [2][4096][8]
  int*   ctrl  = (int*)w;   w += 1024;       // [0]=flag, [8..14]=cnt, [16..22]=off
  int*   list  = (int*)w;   w += 131072;     // [7][4096] token lists
  float* hbuf  = (float*)w; w += 16777216;   // LN out
  char* RA = w;             w += 50331648;   // 48 MB: qkvf | t0,t1 | eo
  char* RB = w;             w += 67108864;   // 64 MB: Sf | ytff | a1
  float* qkvf = (float*)RA;                  // [4096][3072]
  float* t0   = (float*)RA;                  // [4096][1024]
  float* t1   = (float*)(RA + 16777216);     // [4096][1024]
  float* eo   = (float*)RA;                  // [<=9216][1024] expert pair outputs
  float* Sf   = (float*)RB;                  // [16][1024][1024] scores (per batch)
  float* ytff = (float*)RB;                  // [4096][1024] FiLM trunk
  float* a1   = (float*)RB;                  // [4096][4096] adaptor hidden
  int* flag = ctrl;
  int* cnt  = ctrl + 8;
  int* off  = ctrl + 16;

  dim3 blk(256);
  detect_k<<<1, 64, 0, stream>>>(d_in[1], ctrl);
  inx_k<<<16384, blk, 0, stream>>>(d_in[0], flag, x_res);

  for (int l = 0; l < 2; l++) {
    // ---- PreNorm attention ----
    ln_k<<<1024, blk, 0, stream>>>(x_res, d_in[1], d_in[2], l * 1024, flag, hbuf);
    pgemm_k<128,128,64,64,false,0><<<dim3(24, 32, 1), blk, 0, stream>>>(
        hbuf, d_in[3], qkvf, d_in[4], flag, nullptr, nullptr, nullptr, nullptr,
        1024, 1024, 3072, 3072, (long)l * 3145728, (long)l * 3072, 0,
        0, 0, 0, 0, 0, 0, 1, 1.0f);
    zero_k<<<16384, blk, 0, stream>>>(obuf);
    for (int b = 0; b < 4; b++) {
      // scores: z = hq*16 + head (bdiv=16)
      pgemm_k<128,128,64,64,true,0><<<dim3(8, 4, 32), blk, 0, stream>>>(
          qkvf + (long)b * 3145728, qkvf, Sf, nullptr, nullptr,
          nullptr, nullptr, nullptr, nullptr,
          64, 3072, 3072, 1024, (long)b * 3145728 + 1024, 0, 0,
          1572864, 64, 0, 64, 524288, 1048576, 16, 0.125f);
      softmax_k<<<4096, blk, 0, stream>>>(Sf);
      // PV split-K2: z = kk*16 + head; atomicAdd into obuf
      pgemm_k<128,64,64,32,false,4><<<dim3(1, 8, 32), blk, 0, stream>>>(
          Sf, qkvf, obuf + (long)b * 1048576, nullptr, nullptr,
          nullptr, nullptr, nullptr, nullptr,
          512, 1024, 3072, 1024, (long)b * 3145728 + 2048, 0, 0,
          512, 1048576, 1572864, 64, 0, 64, 16, 1.0f);
    }
    pgemm_k<128,64,64,32,false,3><<<dim3(16, 32, 1), blk, 0, stream>>>(
        obuf, d_in[5], x_res, d_in[6], flag, nullptr, nullptr, nullptr, nullptr,
        1024, 1024, 1024, 1024, (long)l * 1048576, (long)l * 1024, 0,
        0, 0, 0, 0, 0, 0, 1, 1.0f);

    // ---- Router + expert lists ----
    float* wl = wts + (long)l * 32768;
    zcnt_k<<<1, 64, 0, stream>>>(cnt);
    router_k<<<1024, blk, 0, stream>>>(x_res, d_in[7], d_in[8],
                                       l * 8192, l * 8, flag, wl, cnt, list);
    off_k<<<1, 64, 0, stream>>>(cnt, off);

    // ---- FiLM trunk ----
    ln_k<<<1024, blk, 0, stream>>>(x_res, d_in[13], d_in[14], l * 1024, flag, hbuf);
    pgemm_k<128,64,64,32,false,0><<<dim3(16, 32, 1), blk, 0, stream>>>(
        hbuf, d_in[15], t0, d_in[16], flag, nullptr, nullptr, nullptr, nullptr,
        1024, 1024, 1024, 1024, (long)l * 1048576, (long)l * 1024, 0,
        0, 0, 0, 0, 0, 0, 1, 1.0f);
    pgemm_k<128,64,64,32,false,0><<<dim3(16, 32, 1), blk, 0, stream>>>(
        hbuf, d_in[17], t1, d_in[18], flag, nullptr, nullptr, nullptr, nullptr,
        1024, 1024, 1024, 1024, (long)l * 1048576, (long)l * 1024, 0,
        0, 0, 0, 0, 0, 0, 1, 1.0f);
    ytf_k<<<16384, blk, 0, stream>>>(t0, t1, wl, ytff, yac);

    // ---- Sparse experts 1..7: gathered GEMMs, one launch each for P and A ----
    pgemm_k<128,128,64,64,false,0><<<dim3(8, 32, 7), blk, 0, stream>>>(
        ytff, d_in[19], eo, d_in[20], flag, list, cnt, off, nullptr,
        1024, 1024, 1024, 1024, (long)l * 7340032, (long)l * 7168, 1024,
        0, 0, 0, 1048576, 0, 0, 1000, 1.0f);
    pgemm_k<128,128,64,64,false,7><<<dim3(8, 32, 7), blk, 0, stream>>>(
        ytff, d_in[21], eo, d_in[22], flag, list, cnt, off, ytff,
        1024, 1024, 1024, 1024, (long)l * 7340032, (long)l * 7168, 1024,
        0, 0, 0, 1048576, 0, 0, 1000, 1.0f);
    scatter_k<<<224, blk, 0, stream>>>(list, cnt, off, wl, eo, yac);

    // ---- Adaptor MLP + residual (full M=4096) ----
    pgemm_k<128,128,64,64,false,2><<<dim3(32, 32, 1), blk, 0, stream>>>(
        yac, d_in[9], a1, d_in[10], flag, nullptr, nullptr, nullptr, nullptr,
        1024, 1024, 4096, 4096, (long)l * 4194304, (long)l * 4096, 0,
        0, 0, 0, 0, 0, 0, 1, 1.0f);
    pgemm_k<128,64,64,32,false,3><<<dim3(16, 32, 1), blk, 0, stream>>>(
        a1, d_in[11], x_res, d_in[12], flag, nullptr, nullptr, nullptr, nullptr,
        4096, 4096, 1024, 1024, (long)l * 4194304, (long)l * 1024, 0,
        0, 0, 0, 0, 0, 0, 1, 1.0f);
  }

  outw_k<<<16640, blk, 0, stream>>>(x_res, wts, flag, d_out);
}